// Round 8
// baseline (364.828 us; speedup 1.0000x reference)
//
#include <hip/hip_runtime.h>
#include <stdint.h>

typedef short bf16x8 __attribute__((ext_vector_type(8)));
typedef float f32x4 __attribute__((ext_vector_type(4)));

#define NROWS 8192
#define DIM   128
// sqrt(10/ln2): dot of scaled z gives 10*cos/ln2, so exp2(dot)=exp(10*cos)
#define ZSCALE 3.7982824f
#define LN2F  0.6931471805599453f

// ===== DIAGNOSTIC ROUND: per-kernel loop multipliers so each kernel's
// dispatch exceeds the ~40us harness fills and appears in rocprof top-5.
// True per-kernel cost = shown dur_us / multiplier. Set all to 1 for prod.
#define NIT_W 64
#define NIT_P 16
#define NIT_S 8
#define NIT_F 64

// opaque pointer launder: defeats cross-iteration CSE of loads (rule #17)
template <typename T>
__device__ __forceinline__ T* opq(T* p) {
  asm volatile("" : "+v"(p));
  return p;
}

// zf layout (fragment-linear): chunk (b, ks) = 1KB at (b*4+ks)*1024 bytes;
// lane l (g=l>>4, q=l&15) holds z[b*16+q][ks*32+g*8 .. +8] as bf16x8.

__device__ __forceinline__ unsigned short f32_to_bf16_bits(float x) {
  union { float f; uint32_t u; } v; v.f = x;
  uint32_t r = v.u + 0x7FFFu + ((v.u >> 16) & 1u);  // RNE
  return (unsigned short)(r >> 16);
}

// K0: Wtf = W in B-fragment order; zero sumexp/topacc. Idempotent -> looped.
__global__ __launch_bounds__(256) void k_wprep(const float* __restrict__ W,
                                               unsigned short* __restrict__ Wtf,
                                               float* __restrict__ sumexp,
                                               float* __restrict__ topacc) {
  const int idx = blockIdx.x * 256 + threadIdx.x;  // grid 64 -> 16384
#pragma unroll 1
  for (int it = 0; it < NIT_W; ++it) {
    const float* Wp = opq(W);
    if (idx < 2048) {
      const int l = idx & 63, chunk = idx >> 6;  // chunk = tj*4+ks
      const int tj = chunk >> 2, ks = chunk & 3, g = l >> 4, q = l & 15;
      const float* wp = Wp + (size_t)(ks * 32 + g * 8) * DIM + tj * 16 + q;
      bf16x8 o;
#pragma unroll
      for (int e = 0; e < 8; ++e) o[e] = (short)f32_to_bf16_bits(wp[(size_t)e * DIM]);
      *(bf16x8*)(Wtf + (size_t)idx * 8) = o;
    }
    if (idx < NROWS) sumexp[idx] = 0.f;
    if (idx == 0) topacc[0] = 0.f;
  }
}

// K1: zf = fragment-order bf16( ZSCALE * normalize(anchor @ W + bias) ).
// Round-6 k-split version: 512 blocks x 4 waves (8 waves/CU); wave wv
// computes K-slice ks=wv, LDS reduce, normalize + fragment-order store.
__global__ __launch_bounds__(256) void k_proj_norm(
    const float* __restrict__ anchor, const unsigned short* __restrict__ Wtf,
    const float* __restrict__ bias, unsigned short* __restrict__ zf) {
  __shared__ float part[4][16][132];  // padded cols
  const int t = threadIdx.x;
  const int wv = t >> 6, l = t & 63, g = l >> 4, q = l & 15;
  const int rb = blockIdx.x * 16;

#pragma unroll 1
  for (int it = 0; it < NIT_P; ++it) {
    const float* anc = opq(anchor);
    const unsigned short* wt = opq(Wtf);

    // A frag (K-slice wv): anchor[rb+q][wv*32+g*8 .. +8]
    const float* ap = anc + (size_t)(rb + q) * DIM + wv * 32 + g * 8;
    const f32x4 a0 = *(const f32x4*)ap, a1 = *(const f32x4*)(ap + 4);
    bf16x8 a;
#pragma unroll
    for (int e = 0; e < 4; ++e) {
      a[e] = (short)f32_to_bf16_bits(a0[e]);
      a[4 + e] = (short)f32_to_bf16_bits(a1[e]);
    }

    f32x4 acc[8];
#pragma unroll
    for (int tj = 0; tj < 8; ++tj) acc[tj] = (f32x4){0.f, 0.f, 0.f, 0.f};
#pragma unroll
    for (int tj = 0; tj < 8; ++tj) {
      const bf16x8 b = *(const bf16x8*)(wt + (size_t)((tj * 4 + wv) * 64 + l) * 8);
      acc[tj] = __builtin_amdgcn_mfma_f32_16x16x32_bf16(a, b, acc[tj], 0, 0, 0);
    }

    // partials: C layout col=q,row=4g+r -> part[wv][4g+r][tj*16+q]
#pragma unroll
    for (int tj = 0; tj < 8; ++tj)
#pragma unroll
      for (int r = 0; r < 4; ++r) part[wv][4 * g + r][tj * 16 + q] = acc[tj][r];
    __syncthreads();

    // reduce k-slices + bias + normalize + fragment-order store
    const int row = t >> 4, c = t & 15;  // c = 8-col chunk
    float v[8];
#pragma unroll
    for (int e = 0; e < 8; ++e) v[e] = bias[c * 8 + e];
#pragma unroll
    for (int s = 0; s < 4; ++s) {
      const f32x4 p0 = *(const f32x4*)&part[s][row][c * 8];
      const f32x4 p1 = *(const f32x4*)&part[s][row][c * 8 + 4];
#pragma unroll
      for (int e = 0; e < 4; ++e) {
        v[e] += p0[e];
        v[4 + e] += p1[e];
      }
    }
    float ss = 0.f;
#pragma unroll
    for (int e = 0; e < 8; ++e) ss += v[e] * v[e];
#pragma unroll
    for (int m = 1; m < 16; m <<= 1) ss += __shfl_xor(ss, m, 64);
    const float inv = ZSCALE / fmaxf(sqrtf(ss), 1e-12f);

    bf16x8 o;
#pragma unroll
    for (int e = 0; e < 8; ++e) o[e] = (short)f32_to_bf16_bits(v[e] * inv);
    const int ks = c >> 2, gg = c & 3;
    *(bf16x8*)(zf + (size_t)(((blockIdx.x * 4 + ks) * 64) + gg * 16 + row) * 8) = o;
    __syncthreads();  // protect part[] reuse across diagnostic iterations
  }
}

// K2: fused Z @ Z^T -> exp2 -> row sums, upper-triangular block tiles (E
// symmetric; off-diag tiles scattered to rows AND cols). MODE 0: diag;
// 1: off-diag; 2: off-diag + positive pairs.
template <int MODE>
__device__ __forceinline__ void simloss_body(
    const unsigned short* __restrict__ zf, float* __restrict__ sumexp,
    float* __restrict__ topacc, const int r0, const int cb, const int l,
    const int g, const int q) {
  bf16x8 afr[4][4];
#pragma unroll
  for (int ti = 0; ti < 4; ++ti)
#pragma unroll
    for (int ks = 0; ks < 4; ++ks)
      afr[ti][ks] = *(const bf16x8*)(
          zf + (size_t)((((r0 >> 4) + ti) * 4 + ks) * 512 + l * 8));

  float sums[4][4];
#pragma unroll
  for (int ti = 0; ti < 4; ++ti)
#pragma unroll
    for (int r = 0; r < 4; ++r) sums[ti][r] = 0.f;
  float topv = 0.f;
  const int posr = r0 + 4096;  // MODE 2 only (igrp<16 -> no wrap)

  bool qeq[4];
#pragma unroll
  for (int r = 0; r < 4; ++r) qeq[r] = (q == 4 * g + r);

  auto LOADB = [&](bf16x8 b[4], int c0) {
    const int bcol = c0 >> 4;
#pragma unroll
    for (int ks = 0; ks < 4; ++ks)
      b[ks] = *(const bf16x8*)(zf + (size_t)((bcol * 4 + ks) * 512 + l * 8));
  };
  auto COMPUTE = [&](const bf16x8 b[4], int c0) {
    f32x4 acc[4];
#pragma unroll
    for (int ti = 0; ti < 4; ++ti) acc[ti] = (f32x4){0.f, 0.f, 0.f, 0.f};
#pragma unroll
    for (int ti = 0; ti < 4; ++ti)
#pragma unroll
      for (int ks = 0; ks < 4; ++ks)
        acc[ti] = __builtin_amdgcn_mfma_f32_16x16x32_bf16(afr[ti][ks], b[ks],
                                                          acc[ti], 0, 0, 0);
    int dgti = -1, psti = -1;
    if (MODE == 0) {
      const int dgo = c0 - r0;
      dgti = ((unsigned)dgo < 64u) ? (dgo >> 4) : -1;
    }
    if (MODE == 2) {
      const int pso = c0 - posr;
      psti = ((unsigned)pso < 64u) ? (pso >> 4) : -1;
    }
    float cs = 0.f;
#pragma unroll
    for (int ti = 0; ti < 4; ++ti)
#pragma unroll
      for (int r = 0; r < 4; ++r) {
        const float d = acc[ti][r];
        float e = __builtin_amdgcn_exp2f(d);
        if (MODE == 0 && ti == dgti && qeq[r]) e = 0.f;    // j == i
        if (MODE == 2 && ti == psti && qeq[r]) topv += d;  // positive pair
        sums[ti][r] += e;
        if (MODE != 0) cs += e;
      }
    if (MODE != 0) {  // col-scatter: symmetric contribution E[j,i]
      cs += __shfl_xor(cs, 16, 64);
      cs += __shfl_xor(cs, 32, 64);
      if (l < 16) atomicAdd(&sumexp[c0 + q], cs);
    }
  };

  bf16x8 bA[4], bB[4];
  LOADB(bA, cb);
#pragma unroll
  for (int p = 0; p < 8; ++p) {
    LOADB(bB, cb + p * 32 + 16);
    COMPUTE(bA, cb + p * 32);
    if (p < 7) LOADB(bA, cb + p * 32 + 32);
    COMPUTE(bB, cb + p * 32 + 16);
  }

#pragma unroll
  for (int ti = 0; ti < 4; ++ti)
#pragma unroll
    for (int r = 0; r < 4; ++r) {
#pragma unroll
      for (int m = 1; m < 16; m <<= 1)
        sums[ti][r] += __shfl_xor(sums[ti][r], m, 64);
    }
  if (q == 0) {
#pragma unroll
    for (int ti = 0; ti < 4; ++ti)
#pragma unroll
      for (int r = 0; r < 4; ++r)
        atomicAdd(&sumexp[r0 + ti * 16 + 4 * g + r], sums[ti][r]);
  }

  if (MODE == 2) {
#pragma unroll
    for (int m = 1; m < 64; m <<= 1) topv += __shfl_xor(topv, m, 64);
    if (l == 0) atomicAdd(topacc, 2.f * topv);
  }
}

// grid = 528 upper-triangular (igrp, jbi>=igrp) block tiles of 256x256.
// Diagnostic loop: iteration 0 -> real accumulators; 1..N -> dummy region.
__global__ __launch_bounds__(256) void k_simloss(
    const unsigned short* __restrict__ zf, float* __restrict__ sumexp,
    float* __restrict__ topacc, float* __restrict__ dummy) {
  const int t = threadIdx.x;
  const int wv = t >> 6, l = t & 63, g = l >> 4, q = l & 15;
  int rem = (int)blockIdx.x, igrp = 0;
  while (rem >= 32 - igrp) { rem -= 32 - igrp; ++igrp; }  // uniform SALU
  const int jbi = igrp + rem;
  const int r0 = igrp * 256 + wv * 64;
  const int cb = jbi * 256;
#pragma unroll 1
  for (int it = 0; it < NIT_S; ++it) {
    const unsigned short* z = opq(zf);
    float* se = (it == 0) ? sumexp : dummy;
    float* ta = (it == 0) ? topacc : dummy + NROWS;
    if (igrp == jbi)           simloss_body<0>(z, se, ta, r0, cb, l, g, q);
    else if (jbi == igrp + 16) simloss_body<2>(z, se, ta, r0, cb, l, g, q);
    else                       simloss_body<1>(z, se, ta, r0, cb, l, g, q);
  }
}

// K3: loss = LN2 * (sum_i log2(bottom_i) - topacc) / (b-1). Idempotent.
__global__ __launch_bounds__(1024) void k_final(const float* __restrict__ sumexp,
                                                const float* __restrict__ topacc,
                                                float* __restrict__ out) {
  __shared__ float red[16];
  const int t = threadIdx.x;
#pragma unroll 1
  for (int it = 0; it < NIT_F; ++it) {
    const float* sep = opq(sumexp);
    float s = 0.f;
    for (int r = t; r < NROWS; r += 1024) s += __log2f(sep[r]);
#pragma unroll
    for (int m = 1; m < 64; m <<= 1) s += __shfl_xor(s, m, 64);
    if ((t & 63) == 0) red[t >> 6] = s;
    __syncthreads();
    if (t == 0) {
      float S1 = 0.f;
#pragma unroll
      for (int i = 0; i < 16; ++i) S1 += red[i];
      out[0] = LN2F * (S1 - topacc[0]) * (1.0f / (float)(NROWS - 1));
    }
    __syncthreads();  // protect red[] across diagnostic iterations
  }
}

extern "C" void kernel_launch(void* const* d_in, const int* in_sizes, int n_in,
                              void* d_out, int out_size, void* d_ws, size_t ws_size,
                              hipStream_t stream) {
  const float* anchor = (const float*)d_in[0];
  const float* W = (const float*)d_in[1];
  const float* bias = (const float*)d_in[2];
  float* out = (float*)d_out;

  char* ws = (char*)d_ws;
  unsigned short* zf = (unsigned short*)ws;                        // 2 MB fragment-order z
  float* sumexp = (float*)(ws + (size_t)2 * 1024 * 1024);          // 32 KB
  float* topacc = (float*)(ws + (size_t)2 * 1024 * 1024 + 32768);  // 4 B
  unsigned short* Wtf = (unsigned short*)(ws + (size_t)2 * 1024 * 1024 + 36864); // 32 KB
  float* dummy = (float*)(ws + (size_t)4 * 1024 * 1024);           // 33 KB diagnostic sink

  k_wprep<<<dim3(64), dim3(256), 0, stream>>>(W, Wtf, sumexp, topacc);
  k_proj_norm<<<dim3(NROWS / 16), dim3(256), 0, stream>>>(anchor, Wtf, bias, zf);
  k_simloss<<<dim3(528), dim3(256), 0, stream>>>(zf, sumexp, topacc, dummy);
  k_final<<<dim3(1), dim3(1024), 0, stream>>>(sumexp, topacc, out);
}

// Round 9
// 113.968 us; speedup vs baseline: 3.2011x; 3.2011x over previous
//
#include <hip/hip_runtime.h>
#include <stdint.h>

typedef short bf16x8 __attribute__((ext_vector_type(8)));
typedef float f32x4 __attribute__((ext_vector_type(4)));

#define NROWS 8192
#define DIM   128
// sqrt(10/ln2): dot of scaled z gives 10*cos/ln2, so exp2(dot)=exp(10*cos)
#define ZSCALE 3.7982824f
#define LN2F  0.6931471805599453f

// zf layout (fragment-linear): chunk (b, ks) = 1KB at (b*4+ks)*1024 bytes;
// lane l (g=l>>4, q=l&15) holds z[b*16+q][ks*32+g*8 .. +8] as bf16x8.

__device__ __forceinline__ unsigned short f32_to_bf16_bits(float x) {
  union { float f; uint32_t u; } v; v.f = x;
  uint32_t r = v.u + 0x7FFFu + ((v.u >> 16) & 1u);  // RNE
  return (unsigned short)(r >> 16);
}

// K0: Wtf = W in B-fragment order; zero sumexp/topacc.
__global__ __launch_bounds__(256) void k_wprep(const float* __restrict__ W,
                                               unsigned short* __restrict__ Wtf,
                                               float* __restrict__ sumexp,
                                               float* __restrict__ topacc) {
  const int idx = blockIdx.x * 256 + threadIdx.x;  // grid 64 -> 16384
  if (idx < 2048) {
    const int l = idx & 63, chunk = idx >> 6;  // chunk = tj*4+ks
    const int tj = chunk >> 2, ks = chunk & 3, g = l >> 4, q = l & 15;
    const float* wp = W + (size_t)(ks * 32 + g * 8) * DIM + tj * 16 + q;
    bf16x8 o;
#pragma unroll
    for (int e = 0; e < 8; ++e) o[e] = (short)f32_to_bf16_bits(wp[(size_t)e * DIM]);
    *(bf16x8*)(Wtf + (size_t)idx * 8) = o;
  }
  if (idx < NROWS) sumexp[idx] = 0.f;
  if (idx == 0) topacc[0] = 0.f;
}

// K1: zf = fragment-order bf16( ZSCALE * normalize(anchor @ W + bias) ).
// R6 k-split version: 512 blocks x 4 waves; wave wv computes K-slice ks=wv,
// LDS reduce, normalize + fragment-order store.
__global__ __launch_bounds__(256) void k_proj_norm(
    const float* __restrict__ anchor, const unsigned short* __restrict__ Wtf,
    const float* __restrict__ bias, unsigned short* __restrict__ zf) {
  __shared__ float part[4][16][132];  // padded cols
  const int t = threadIdx.x;
  const int wv = t >> 6, l = t & 63, g = l >> 4, q = l & 15;
  const int rb = blockIdx.x * 16;

  // A frag (K-slice wv): anchor[rb+q][wv*32+g*8 .. +8]
  const float* ap = anchor + (size_t)(rb + q) * DIM + wv * 32 + g * 8;
  const f32x4 a0 = *(const f32x4*)ap, a1 = *(const f32x4*)(ap + 4);
  bf16x8 a;
#pragma unroll
  for (int e = 0; e < 4; ++e) {
    a[e] = (short)f32_to_bf16_bits(a0[e]);
    a[4 + e] = (short)f32_to_bf16_bits(a1[e]);
  }

  f32x4 acc[8];
#pragma unroll
  for (int tj = 0; tj < 8; ++tj) acc[tj] = (f32x4){0.f, 0.f, 0.f, 0.f};
#pragma unroll
  for (int tj = 0; tj < 8; ++tj) {
    const bf16x8 b = *(const bf16x8*)(Wtf + (size_t)((tj * 4 + wv) * 64 + l) * 8);
    acc[tj] = __builtin_amdgcn_mfma_f32_16x16x32_bf16(a, b, acc[tj], 0, 0, 0);
  }

  // partials: C layout col=q,row=4g+r -> part[wv][4g+r][tj*16+q]
#pragma unroll
  for (int tj = 0; tj < 8; ++tj)
#pragma unroll
    for (int r = 0; r < 4; ++r) part[wv][4 * g + r][tj * 16 + q] = acc[tj][r];
  __syncthreads();

  // reduce k-slices + bias + normalize + fragment-order store
  const int row = t >> 4, c = t & 15;  // c = 8-col chunk
  float v[8];
#pragma unroll
  for (int e = 0; e < 8; ++e) v[e] = bias[c * 8 + e];
#pragma unroll
  for (int s = 0; s < 4; ++s) {
    const f32x4 p0 = *(const f32x4*)&part[s][row][c * 8];
    const f32x4 p1 = *(const f32x4*)&part[s][row][c * 8 + 4];
#pragma unroll
    for (int e = 0; e < 4; ++e) {
      v[e] += p0[e];
      v[4 + e] += p1[e];
    }
  }
  float ss = 0.f;
#pragma unroll
  for (int e = 0; e < 8; ++e) ss += v[e] * v[e];
#pragma unroll
  for (int m = 1; m < 16; m <<= 1) ss += __shfl_xor(ss, m, 64);
  const float inv = ZSCALE / fmaxf(sqrtf(ss), 1e-12f);

  bf16x8 o;
#pragma unroll
  for (int e = 0; e < 8; ++e) o[e] = (short)f32_to_bf16_bits(v[e] * inv);
  const int ks = c >> 2, gg = c & 3;
  *(bf16x8*)(zf + (size_t)(((blockIdx.x * 4 + ks) * 64) + gg * 16 + row) * 8) = o;
}

// K2: fused Z @ Z^T -> exp2 -> row+col sums, upper-triangular 256x256 block
// tiles (E symmetric). 8 waves x 32 i-rows per block; col-sums accumulate in
// colacc[16] registers (static step index) and scatter ONCE at kernel end
// (no shfl/atomic inside the inner loop). MODE 0: diag; 1: off; 2: off+pos.
template <int MODE>
__device__ __forceinline__ void simloss_body(
    const unsigned short* __restrict__ zf, float* __restrict__ sumexp,
    float* __restrict__ topacc, const int r0, const int cb, const int l,
    const int g, const int q) {
  // A frags: afr[ti][ks] for rows r0+ti*16+q (lane-linear, 32 VGPR)
  bf16x8 afr[2][4];
#pragma unroll
  for (int ti = 0; ti < 2; ++ti)
#pragma unroll
    for (int ks = 0; ks < 4; ++ks)
      afr[ti][ks] = *(const bf16x8*)(
          zf + (size_t)((((r0 >> 4) + ti) * 4 + ks) * 512 + l * 8));

  float sums[2][4] = {{0.f, 0.f, 0.f, 0.f}, {0.f, 0.f, 0.f, 0.f}};
  float colacc[16];
#pragma unroll
  for (int p = 0; p < 16; ++p) colacc[p] = 0.f;
  float topv = 0.f;
  const int posr = r0 + 4096;  // MODE 2 only (igrp<16 -> no wrap)

  bool qeq[4];
#pragma unroll
  for (int r = 0; r < 4; ++r) qeq[r] = (q == 4 * g + r);

  auto LOADB = [&](bf16x8 b[4], int c0) {
    const int bcol = c0 >> 4;
#pragma unroll
    for (int ks = 0; ks < 4; ++ks)
      b[ks] = *(const bf16x8*)(zf + (size_t)((bcol * 4 + ks) * 512 + l * 8));
  };
  auto COMPUTE = [&](const bf16x8 b[4], int c0, int step) {
    f32x4 acc[2];
    acc[0] = (f32x4){0.f, 0.f, 0.f, 0.f};
    acc[1] = acc[0];
#pragma unroll
    for (int ti = 0; ti < 2; ++ti)
#pragma unroll
      for (int ks = 0; ks < 4; ++ks)
        acc[ti] = __builtin_amdgcn_mfma_f32_16x16x32_bf16(afr[ti][ks], b[ks],
                                                          acc[ti], 0, 0, 0);
    int dgti = -1, psti = -1;
    if (MODE == 0) {
      const int dgo = c0 - r0;
      dgti = ((unsigned)dgo < 32u) ? (dgo >> 4) : -1;
    }
    if (MODE == 2) {
      const int pso = c0 - posr;
      psti = ((unsigned)pso < 32u) ? (pso >> 4) : -1;
    }
    float cs = 0.f;
#pragma unroll
    for (int ti = 0; ti < 2; ++ti)
#pragma unroll
      for (int r = 0; r < 4; ++r) {
        const float d = acc[ti][r];
        float e = __builtin_amdgcn_exp2f(d);
        if (MODE == 0 && ti == dgti && qeq[r]) e = 0.f;    // j == i
        if (MODE == 2 && ti == psti && qeq[r]) topv += d;  // positive pair
        sums[ti][r] += e;
        if (MODE != 0) cs += e;
      }
    if (MODE != 0) colacc[step] += cs;  // step is unroll-constant -> register
  };

  // 16 j-steps of 16 cols, 2-deep register pipeline (static names)
  bf16x8 bA[4], bB[4];
  LOADB(bA, cb);
#pragma unroll
  for (int p = 0; p < 8; ++p) {
    LOADB(bB, cb + p * 32 + 16);
    COMPUTE(bA, cb + p * 32, 2 * p);
    if (p < 7) LOADB(bA, cb + p * 32 + 32);
    COMPUTE(bB, cb + p * 32 + 16, 2 * p + 1);
  }

  // row-sum reduce across the 16 q-lanes
#pragma unroll
  for (int ti = 0; ti < 2; ++ti)
#pragma unroll
    for (int r = 0; r < 4; ++r) {
#pragma unroll
      for (int m = 1; m < 16; m <<= 1)
        sums[ti][r] += __shfl_xor(sums[ti][r], m, 64);
    }
  if (q == 0) {
#pragma unroll
    for (int ti = 0; ti < 2; ++ti)
#pragma unroll
      for (int r = 0; r < 4; ++r)
        atomicAdd(&sumexp[r0 + ti * 16 + 4 * g + r], sums[ti][r]);
  }

  if (MODE != 0) {
    // batched col-sum reduce over the 4 g-lanes: 32 INDEPENDENT shfls
#pragma unroll
    for (int p = 0; p < 16; ++p) {
      colacc[p] += __shfl_xor(colacc[p], 16, 64);
      colacc[p] += __shfl_xor(colacc[p], 32, 64);
    }
    if (l < 16) {
#pragma unroll
      for (int p = 0; p < 16; ++p)
        atomicAdd(&sumexp[cb + p * 16 + q], colacc[p]);
    }
  }

  if (MODE == 2) {  // each pair element counts for both rows' tops
#pragma unroll
    for (int m = 1; m < 64; m <<= 1) topv += __shfl_xor(topv, m, 64);
    if (l == 0) atomicAdd(topacc, 2.f * topv);
  }
}

// grid = 528 upper-triangular (igrp, jbi>=igrp) 256x256 tiles; 512 threads.
__global__ __launch_bounds__(512, 4) void k_simloss(
    const unsigned short* __restrict__ zf, float* __restrict__ sumexp,
    float* __restrict__ topacc) {
  const int t = threadIdx.x;
  const int wv = t >> 6, l = t & 63, g = l >> 4, q = l & 15;
  int rem = (int)blockIdx.x, igrp = 0;
  while (rem >= 32 - igrp) { rem -= 32 - igrp; ++igrp; }  // uniform SALU
  const int jbi = igrp + rem;
  const int r0 = igrp * 256 + wv * 32;  // wave's 32 i-rows
  const int cb = jbi * 256;             // block's 256 j-cols
  if (igrp == jbi)           simloss_body<0>(zf, sumexp, topacc, r0, cb, l, g, q);
  else if (jbi == igrp + 16) simloss_body<2>(zf, sumexp, topacc, r0, cb, l, g, q);
  else                       simloss_body<1>(zf, sumexp, topacc, r0, cb, l, g, q);
}

// K3: loss = LN2 * (sum_i log2(bottom_i) - topacc) / (b-1)
__global__ __launch_bounds__(1024) void k_final(const float* __restrict__ sumexp,
                                                const float* __restrict__ topacc,
                                                float* __restrict__ out) {
  __shared__ float red[16];
  const int t = threadIdx.x;
  float s = 0.f;
  for (int r = t; r < NROWS; r += 1024) s += __log2f(sumexp[r]);
#pragma unroll
  for (int m = 1; m < 64; m <<= 1) s += __shfl_xor(s, m, 64);
  if ((t & 63) == 0) red[t >> 6] = s;
  __syncthreads();
  if (t == 0) {
    float S1 = 0.f;
#pragma unroll
    for (int i = 0; i < 16; ++i) S1 += red[i];
    out[0] = LN2F * (S1 - topacc[0]) * (1.0f / (float)(NROWS - 1));
  }
}

extern "C" void kernel_launch(void* const* d_in, const int* in_sizes, int n_in,
                              void* d_out, int out_size, void* d_ws, size_t ws_size,
                              hipStream_t stream) {
  const float* anchor = (const float*)d_in[0];
  const float* W = (const float*)d_in[1];
  const float* bias = (const float*)d_in[2];
  float* out = (float*)d_out;

  char* ws = (char*)d_ws;
  unsigned short* zf = (unsigned short*)ws;                        // 2 MB fragment-order z
  float* sumexp = (float*)(ws + (size_t)2 * 1024 * 1024);          // 32 KB
  float* topacc = (float*)(ws + (size_t)2 * 1024 * 1024 + 32768);  // 4 B
  unsigned short* Wtf = (unsigned short*)(ws + (size_t)2 * 1024 * 1024 + 36864); // 32 KB

  k_wprep<<<dim3(64), dim3(256), 0, stream>>>(W, Wtf, sumexp, topacc);
  k_proj_norm<<<dim3(NROWS / 16), dim3(256), 0, stream>>>(anchor, Wtf, bias, zf);
  k_simloss<<<dim3(528), dim3(512), 0, stream>>>(zf, sumexp, topacc);
  k_final<<<dim3(1), dim3(1024), 0, stream>>>(sumexp, topacc, out);
}

// Round 10
// 43.224 us; speedup vs baseline: 8.4403x; 2.6367x over previous
//
#include <hip/hip_runtime.h>
#include <stdint.h>

typedef short bf16x8 __attribute__((ext_vector_type(8)));
typedef float f32x4 __attribute__((ext_vector_type(4)));

#define NROWS 8192
#define DIM   128
// sqrt(10/ln2): dot of scaled z gives 10*cos/ln2, so exp2(dot)=exp(10*cos)
#define ZSCALE 3.7982824f
#define LN2F  0.6931471805599453f

// zf layout (fragment-linear): chunk (b, ks) = 1KB at (b*4+ks)*1024 bytes;
// lane l (g=l>>4, q=l&15) holds z[b*16+q][ks*32+g*8 .. +8] as bf16x8.

__device__ __forceinline__ unsigned short f32_to_bf16_bits(float x) {
  union { float f; uint32_t u; } v; v.f = x;
  uint32_t r = v.u + 0x7FFFu + ((v.u >> 16) & 1u);  // RNE
  return (unsigned short)(r >> 16);
}

// K0: Wtf = W in B-fragment order; zero sumexp/topacc.
__global__ __launch_bounds__(256) void k_wprep(const float* __restrict__ W,
                                               unsigned short* __restrict__ Wtf,
                                               float* __restrict__ sumexp,
                                               float* __restrict__ topacc) {
  const int idx = blockIdx.x * 256 + threadIdx.x;  // grid 64 -> 16384
  if (idx < 2048) {
    const int l = idx & 63, chunk = idx >> 6;  // chunk = tj*4+ks
    const int tj = chunk >> 2, ks = chunk & 3, g = l >> 4, q = l & 15;
    const float* wp = W + (size_t)(ks * 32 + g * 8) * DIM + tj * 16 + q;
    bf16x8 o;
#pragma unroll
    for (int e = 0; e < 8; ++e) o[e] = (short)f32_to_bf16_bits(wp[(size_t)e * DIM]);
    *(bf16x8*)(Wtf + (size_t)idx * 8) = o;
  }
  if (idx < NROWS) sumexp[idx] = 0.f;
  if (idx == 0) topacc[0] = 0.f;
}

// K1: zf = fragment-order bf16( ZSCALE * normalize(anchor @ W + bias) ).
// 512 blocks x 4 waves; wave wv computes K-slice ks=wv, LDS reduce,
// normalize + fragment-order store.
__global__ __launch_bounds__(256) void k_proj_norm(
    const float* __restrict__ anchor, const unsigned short* __restrict__ Wtf,
    const float* __restrict__ bias, unsigned short* __restrict__ zf) {
  __shared__ float part[4][16][132];  // padded cols
  const int t = threadIdx.x;
  const int wv = t >> 6, l = t & 63, g = l >> 4, q = l & 15;
  const int rb = blockIdx.x * 16;

  // A frag (K-slice wv): anchor[rb+q][wv*32+g*8 .. +8]
  const float* ap = anchor + (size_t)(rb + q) * DIM + wv * 32 + g * 8;
  const f32x4 a0 = *(const f32x4*)ap, a1 = *(const f32x4*)(ap + 4);
  bf16x8 a;
#pragma unroll
  for (int e = 0; e < 4; ++e) {
    a[e] = (short)f32_to_bf16_bits(a0[e]);
    a[4 + e] = (short)f32_to_bf16_bits(a1[e]);
  }

  f32x4 acc[8];
#pragma unroll
  for (int tj = 0; tj < 8; ++tj) acc[tj] = (f32x4){0.f, 0.f, 0.f, 0.f};
#pragma unroll
  for (int tj = 0; tj < 8; ++tj) {
    const bf16x8 b = *(const bf16x8*)(Wtf + (size_t)((tj * 4 + wv) * 64 + l) * 8);
    acc[tj] = __builtin_amdgcn_mfma_f32_16x16x32_bf16(a, b, acc[tj], 0, 0, 0);
  }

  // partials: C layout col=q,row=4g+r -> part[wv][4g+r][tj*16+q]
#pragma unroll
  for (int tj = 0; tj < 8; ++tj)
#pragma unroll
    for (int r = 0; r < 4; ++r) part[wv][4 * g + r][tj * 16 + q] = acc[tj][r];
  __syncthreads();

  // reduce k-slices + bias + normalize + fragment-order store
  const int row = t >> 4, c = t & 15;  // c = 8-col chunk
  float v[8];
#pragma unroll
  for (int e = 0; e < 8; ++e) v[e] = bias[c * 8 + e];
#pragma unroll
  for (int s = 0; s < 4; ++s) {
    const f32x4 p0 = *(const f32x4*)&part[s][row][c * 8];
    const f32x4 p1 = *(const f32x4*)&part[s][row][c * 8 + 4];
#pragma unroll
    for (int e = 0; e < 4; ++e) {
      v[e] += p0[e];
      v[4 + e] += p1[e];
    }
  }
  float ss = 0.f;
#pragma unroll
  for (int e = 0; e < 8; ++e) ss += v[e] * v[e];
#pragma unroll
  for (int m = 1; m < 16; m <<= 1) ss += __shfl_xor(ss, m, 64);
  const float inv = ZSCALE / fmaxf(sqrtf(ss), 1e-12f);

  bf16x8 o;
#pragma unroll
  for (int e = 0; e < 8; ++e) o[e] = (short)f32_to_bf16_bits(v[e] * inv);
  const int ks = c >> 2, gg = c & 3;
  *(bf16x8*)(zf + (size_t)(((blockIdx.x * 4 + ks) * 64) + gg * 16 + row) * 8) = o;
}

// K2: fused Z @ Z^T -> exp2 -> row+col sums, upper-triangular 256x256 block
// tiles (E symmetric). 8 waves x 32 i-rows per block; col-sums accumulate in
// colacc[16] registers (static step index) and scatter ONCE at kernel end.
// MODE 0: diag; 1: off; 2: off+pos.
template <int MODE>
__device__ __forceinline__ void simloss_body(
    const unsigned short* __restrict__ zf, float* __restrict__ sumexp,
    float* __restrict__ topacc, const int r0, const int cb, const int l,
    const int g, const int q) {
  // A frags: afr[ti][ks] for rows r0+ti*16+q (lane-linear, 32 VGPR)
  bf16x8 afr[2][4];
#pragma unroll
  for (int ti = 0; ti < 2; ++ti)
#pragma unroll
    for (int ks = 0; ks < 4; ++ks)
      afr[ti][ks] = *(const bf16x8*)(
          zf + (size_t)((((r0 >> 4) + ti) * 4 + ks) * 512 + l * 8));

  float sums[2][4] = {{0.f, 0.f, 0.f, 0.f}, {0.f, 0.f, 0.f, 0.f}};
  float colacc[16];
#pragma unroll
  for (int p = 0; p < 16; ++p) colacc[p] = 0.f;
  float topv = 0.f;
  const int posr = r0 + 4096;  // MODE 2 only (igrp<16 -> no wrap)

  bool qeq[4];
#pragma unroll
  for (int r = 0; r < 4; ++r) qeq[r] = (q == 4 * g + r);

  auto LOADB = [&](bf16x8 b[4], int c0) {
    const int bcol = c0 >> 4;
#pragma unroll
    for (int ks = 0; ks < 4; ++ks)
      b[ks] = *(const bf16x8*)(zf + (size_t)((bcol * 4 + ks) * 512 + l * 8));
  };
  auto COMPUTE = [&](const bf16x8 b[4], int c0, int step) {
    f32x4 acc[2];
    acc[0] = (f32x4){0.f, 0.f, 0.f, 0.f};
    acc[1] = acc[0];
#pragma unroll
    for (int ti = 0; ti < 2; ++ti)
#pragma unroll
      for (int ks = 0; ks < 4; ++ks)
        acc[ti] = __builtin_amdgcn_mfma_f32_16x16x32_bf16(afr[ti][ks], b[ks],
                                                          acc[ti], 0, 0, 0);
    int dgti = -1, psti = -1;
    if (MODE == 0) {
      const int dgo = c0 - r0;
      dgti = ((unsigned)dgo < 32u) ? (dgo >> 4) : -1;
    }
    if (MODE == 2) {
      const int pso = c0 - posr;
      psti = ((unsigned)pso < 32u) ? (pso >> 4) : -1;
    }
    float cs = 0.f;
#pragma unroll
    for (int ti = 0; ti < 2; ++ti)
#pragma unroll
      for (int r = 0; r < 4; ++r) {
        const float d = acc[ti][r];
        float e = __builtin_amdgcn_exp2f(d);
        if (MODE == 0 && ti == dgti && qeq[r]) e = 0.f;    // j == i
        if (MODE == 2 && ti == psti && qeq[r]) topv += d;  // positive pair
        sums[ti][r] += e;
        if (MODE != 0) cs += e;
      }
    if (MODE != 0) colacc[step] += cs;  // step is unroll-constant -> register
  };

  // 16 j-steps of 16 cols, 2-deep register pipeline (static names)
  bf16x8 bA[4], bB[4];
  LOADB(bA, cb);
#pragma unroll
  for (int p = 0; p < 8; ++p) {
    LOADB(bB, cb + p * 32 + 16);
    COMPUTE(bA, cb + p * 32, 2 * p);
    if (p < 7) LOADB(bA, cb + p * 32 + 32);
    COMPUTE(bB, cb + p * 32 + 16, 2 * p + 1);
  }

  // row-sum reduce across the 16 q-lanes
#pragma unroll
  for (int ti = 0; ti < 2; ++ti)
#pragma unroll
    for (int r = 0; r < 4; ++r) {
#pragma unroll
      for (int m = 1; m < 16; m <<= 1)
        sums[ti][r] += __shfl_xor(sums[ti][r], m, 64);
    }
  if (q == 0) {
#pragma unroll
    for (int ti = 0; ti < 2; ++ti)
#pragma unroll
      for (int r = 0; r < 4; ++r)
        atomicAdd(&sumexp[r0 + ti * 16 + 4 * g + r], sums[ti][r]);
  }

  if (MODE != 0) {
    // batched col-sum reduce over the 4 g-lanes: 32 INDEPENDENT shfls
#pragma unroll
    for (int p = 0; p < 16; ++p) {
      colacc[p] += __shfl_xor(colacc[p], 16, 64);
      colacc[p] += __shfl_xor(colacc[p], 32, 64);
    }
    if (l < 16) {
#pragma unroll
      for (int p = 0; p < 16; ++p)
        atomicAdd(&sumexp[cb + p * 16 + q], colacc[p]);
    }
  }

  if (MODE == 2) {  // each pair element counts for both rows' tops
#pragma unroll
    for (int m = 1; m < 64; m <<= 1) topv += __shfl_xor(topv, m, 64);
    if (l == 0) atomicAdd(topacc, 2.f * topv);
  }
}

// grid = 528 upper-triangular (igrp, jbi>=igrp) 256x256 tiles; 512 threads.
// NOTE: no min-waves in launch_bounds — R9's (512,4) capped VGPR at 64 and
// spilled colacc/bA/bB to scratch (217 MB WRITE_SIZE). Let the allocator
// pick (~110-130 VGPR -> 4 waves/SIMD, zero spill).
__global__ __launch_bounds__(512) void k_simloss(
    const unsigned short* __restrict__ zf, float* __restrict__ sumexp,
    float* __restrict__ topacc) {
  const int t = threadIdx.x;
  const int wv = t >> 6, l = t & 63, g = l >> 4, q = l & 15;
  int rem = (int)blockIdx.x, igrp = 0;
  while (rem >= 32 - igrp) { rem -= 32 - igrp; ++igrp; }  // uniform SALU
  const int jbi = igrp + rem;
  const int r0 = igrp * 256 + wv * 32;  // wave's 32 i-rows
  const int cb = jbi * 256;             // block's 256 j-cols
  if (igrp == jbi)           simloss_body<0>(zf, sumexp, topacc, r0, cb, l, g, q);
  else if (jbi == igrp + 16) simloss_body<2>(zf, sumexp, topacc, r0, cb, l, g, q);
  else                       simloss_body<1>(zf, sumexp, topacc, r0, cb, l, g, q);
}

// K3: loss = LN2 * (sum_i log2(bottom_i) - topacc) / (b-1)
__global__ __launch_bounds__(1024) void k_final(const float* __restrict__ sumexp,
                                                const float* __restrict__ topacc,
                                                float* __restrict__ out) {
  __shared__ float red[16];
  const int t = threadIdx.x;
  float s = 0.f;
  for (int r = t; r < NROWS; r += 1024) s += __log2f(sumexp[r]);
#pragma unroll
  for (int m = 1; m < 64; m <<= 1) s += __shfl_xor(s, m, 64);
  if ((t & 63) == 0) red[t >> 6] = s;
  __syncthreads();
  if (t == 0) {
    float S1 = 0.f;
#pragma unroll
    for (int i = 0; i < 16; ++i) S1 += red[i];
    out[0] = LN2F * (S1 - topacc[0]) * (1.0f / (float)(NROWS - 1));
  }
}

extern "C" void kernel_launch(void* const* d_in, const int* in_sizes, int n_in,
                              void* d_out, int out_size, void* d_ws, size_t ws_size,
                              hipStream_t stream) {
  const float* anchor = (const float*)d_in[0];
  const float* W = (const float*)d_in[1];
  const float* bias = (const float*)d_in[2];
  float* out = (float*)d_out;

  char* ws = (char*)d_ws;
  unsigned short* zf = (unsigned short*)ws;                        // 2 MB fragment-order z
  float* sumexp = (float*)(ws + (size_t)2 * 1024 * 1024);          // 32 KB
  float* topacc = (float*)(ws + (size_t)2 * 1024 * 1024 + 32768);  // 4 B
  unsigned short* Wtf = (unsigned short*)(ws + (size_t)2 * 1024 * 1024 + 36864); // 32 KB

  k_wprep<<<dim3(64), dim3(256), 0, stream>>>(W, Wtf, sumexp, topacc);
  k_proj_norm<<<dim3(NROWS / 16), dim3(256), 0, stream>>>(anchor, Wtf, bias, zf);
  k_simloss<<<dim3(528), dim3(512), 0, stream>>>(zf, sumexp, topacc);
  k_final<<<dim3(1), dim3(1024), 0, stream>>>(sumexp, topacc, out);
}